// Round 2
// baseline (415.914 us; speedup 1.0000x reference)
//
#include <hip/hip_runtime.h>

#define NPTS   32768
#define NCODES 8192
#define DIM    256

#define DECAYF 0.99f
#define ONE_MINUS_DECAYF ((float)(1.0 - 0.99))
#define EPSF   1e-5f
#define KEPSF  ((float)(8192.0 * 1e-5))
#define MARGIN 0.05f

// workspace byte offsets
#define WS_PART  0                                     // fp64 [8192] loss partials
#define WS_A     (WS_PART + NPTS / 4 * 8)              // fp32 [NPTS]
#define WS_EN    (WS_A + NPTS * 4)                     // fp32 [NCODES]
#define WS_CNT   (WS_EN + NCODES * 4)                  // int  [NCODES]
#define WS_S     (WS_CNT + NCODES * 4)                 // fp32 [NCODES] smoothed
#define WS_IDX   (WS_S + NCODES * 4)                   // int  [NPTS]
#define WS_OFFS  (WS_IDX + NPTS * 4)                   // int  [NCODES]
#define WS_CUR   (WS_OFFS + NCODES * 4)                // int  [NCODES]
#define WS_PLIST (WS_CUR + NCODES * 4)                 // int  [NPTS]
#define WS_EMBT  (WS_PLIST + NPTS * 4)                 // (unused, kept for layout)
#define WS_GMIN  (WS_EMBT + (size_t)DIM * NCODES * 4)  // fp32 [NPTS][512]     64 MB
#define WS_AH    (WS_GMIN + (size_t)NPTS * 512 * 4)    // bf16 [NPTS][256]     16 MB
#define WS_BH    (WS_AH + (size_t)NPTS * DIM * 2)      // bf16 [NCODES][256]    4 MB

typedef __attribute__((ext_vector_type(8))) short short8;
typedef __attribute__((ext_vector_type(4))) float f32x4;

__device__ inline void gl_lds16(const void* g, void* l) {
    __builtin_amdgcn_global_load_lds(
        (const __attribute__((address_space(1))) void*)g,
        (__attribute__((address_space(3))) void*)l, 16, 0, 0);
}

__device__ inline unsigned short f2bf(float f) {  // RNE float->bf16
    unsigned u = __float_as_uint(f);
    return (unsigned short)((u + 0x7FFFu + ((u >> 16) & 1u)) >> 16);
}
__device__ inline unsigned f2ord(float f) {       // monotone float->uint
    unsigned u = __float_as_uint(f);
    return (u & 0x80000000u) ? ~u : (u | 0x80000000u);
}

// ---------------------------------------------------------------------------
__global__ __launch_bounds__(256) void k_prep0(int* __restrict__ cnt) {
    int i = blockIdx.x * blockDim.x + threadIdx.x;
    if (i < NCODES) cnt[i] = 0;
}

// ---------------------------------------------------------------------------
__global__ __launch_bounds__(256) void k_rownorm(const float* __restrict__ x,
                                                 float* __restrict__ outn,
                                                 int nrows) {
    int w = (blockIdx.x * blockDim.x + threadIdx.x) >> 6;
    int lane = threadIdx.x & 63;
    if (w >= nrows) return;
    const float4 v = *(const float4*)(x + (size_t)w * DIM + 4 * lane);
    float q0 = v.x * v.x, q1 = v.y * v.y, q2 = v.z * v.z, q3 = v.w * v.w;
    double s = (double)q0 + (double)q1 + (double)q2 + (double)q3;
    #pragma unroll
    for (int off = 32; off > 0; off >>= 1) s += __shfl_down(s, off);
    if (lane == 0) outn[w] = (float)s;
}

// ---------------------------------------------------------------------------
// elementwise fp32 -> bf16-hi
__global__ __launch_bounds__(256) void k_split(const float* __restrict__ x,
                                               unsigned short* __restrict__ dst,
                                               int nelem) {
    int i = blockIdx.x * blockDim.x + threadIdx.x;
    int stride = gridDim.x * blockDim.x;
    for (int j = i; j < nelem; j += stride)
        dst[j] = f2bf(x[j]);
}

// ---------------------------------------------------------------------------
// Phase 1: bf16-hi MFMA GEMM, 256x256 tile, 8-phase schedule (T2+T3+T4+T5).
// Operands SWAPPED vs reference: M = codes (MFMA A), N = points (MFMA B), so
// C/D rows = codes -> the per-16-code group min is 3 in-reg fmin + 2 shfl.
// gmin groups are LINEAR: group g holds codes [g*16, g*16+16).
//
// Schedule per K-tile kt (buf = kt&1, 4 phases):
//  ph1 (mh0,nh0): ds_read af0(8)+bf0(4); stage A1[kt+1]->other buf
//  ph2 (mh0,nh1): ds_read bf1(4);        stage B1[kt+1]->other buf
//  ph3 (mh1,nh0): ds_read af1(8);        stage A0[kt+2]->THIS buf (A-mh0 rows,
//                                        dead since ph1 -- register reuse)
//  ph4 (mh1,nh1): no ds_read;            stage B0[kt+2]->THIS buf (B-nh0 rows,
//                                        dead since ph1); vmcnt(4); barrier
// In-flight ledger: vmcnt(4) at each K-tile end leaves only {A0,B0}[kt+2]
// outstanding => every region landed >= 1 full K-tile before first read.
__global__ __launch_bounds__(512, 2) void k_gemm_argmin(
    const unsigned short* __restrict__ Ah,    // points [NPTS][256] bf16 bits
    const unsigned short* __restrict__ Bh,    // codes  [NCODES][256] bf16 bits
    const float* __restrict__ en,
    float* __restrict__ gmin);                // [NPTS][512]

template<int MH>
__device__ __forceinline__ void dsr_a(const unsigned short* LB, int wr, int l15,
                                      int l7, int quad, short8 (&af)[4][2]) {
#pragma unroll
    for (int m4 = 0; m4 < 4; ++m4) {
        const int r = wr * 128 + (MH * 4 + m4) * 16 + l15;
#pragma unroll
        for (int kk = 0; kk < 2; ++kk)
            af[m4][kk] = *(const short8*)&LB[(r * 8 + ((kk * 4 + quad) ^ l7)) * 8];
    }
}
template<int NH>
__device__ __forceinline__ void dsr_b(const unsigned short* LB, int wc, int l15,
                                      int l7, int quad, short8 (&bf)[2][2]) {
#pragma unroll
    for (int n2 = 0; n2 < 2; ++n2) {
        const int r = wc * 64 + (NH * 2 + n2) * 16 + l15;
#pragma unroll
        for (int kk = 0; kk < 2; ++kk)
            bf[n2][kk] = *(const short8*)&LB[16384 + (r * 8 + ((kk * 4 + quad) ^ l7)) * 8];
    }
}
template<int MH, int NH>
__device__ __forceinline__ void mma8(const short8 (&af)[4][2], const short8 (&bf)[2][2],
                                     f32x4 (&acc)[8][4]) {
#pragma unroll
    for (int m4 = 0; m4 < 4; ++m4)
#pragma unroll
        for (int n2 = 0; n2 < 2; ++n2)
#pragma unroll
            for (int kk = 0; kk < 2; ++kk)
                acc[MH * 4 + m4][NH * 2 + n2] = __builtin_amdgcn_mfma_f32_16x16x32_bf16(
                    af[m4][kk], bf[n2][kk], acc[MH * 4 + m4][NH * 2 + n2], 0, 0, 0);
}

__global__ __launch_bounds__(512, 2) void k_gemm_argmin(
    const unsigned short* __restrict__ Ah,
    const unsigned short* __restrict__ Bh,
    const float* __restrict__ en,
    float* __restrict__ gmin) {
    __shared__ __align__(16) unsigned short LDS[65536];  // 128 KB: 2 bufs x (A 32K | B 32K)

    const int t = threadIdx.x;
    const int w = t >> 6, l = t & 63;
    const int quad = l >> 4, l15 = l & 15, l7 = l & 7;
    const int wr = w >> 2, wc = w & 3;
    const int cb = blockIdx.x & 31, pb = blockIdx.x >> 5;  // codes-fastest
    const int cBase = cb * 256, pBase = pb * 256;

    // staging geometry: chunk = 1024 slots of 16B; thread covers slots t, t+512
    // swizzle: element (row, kc) stored at slot (row*8 + (kc ^ (row&7)));
    // staged via pre-swizzled global source + linear LDS dest.
    const int lrs0 = t >> 3;                       // [0,64)
    const int xg = (t & 7) ^ (lrs0 & 7);
    const int rA0s0 = lrs0;                        // A0 rows {0-63}
    const int rA0s1 = 128 + lrs0;                  //          {128-191}
    const int rB0s0 = (lrs0 & 31) | ((lrs0 >> 5) << 6);  // B0 rows {0-31,64-95}
    const int rB0s1 = 128 + rB0s0;                 //          {128-159,192-223}

    const unsigned short* gA0s0 = Bh + (size_t)(cBase + rA0s0) * DIM + xg * 8;
    const unsigned short* gA0s1 = Bh + (size_t)(cBase + rA0s1) * DIM + xg * 8;
    const unsigned short* gB0s0 = Ah + (size_t)(pBase + rB0s0) * DIM + xg * 8;
    const unsigned short* gB0s1 = Ah + (size_t)(pBase + rB0s1) * DIM + xg * 8;

    // wave-uniform LDS dest bases (short offsets; row stride = 64 shorts)
    const int dA0s0 = (w * 8) * 64;
    const int dA0s1 = (128 + w * 8) * 64;
    const int dB0s0 = (((w & 3) * 8) | ((w >> 2) << 6)) * 64;
    const int dB0s1 = dB0s0 + 128 * 64;

#define STG_A0(KT, BUFS) do { \
        gl_lds16(gA0s0 + (KT) * 64, &LDS[(BUFS) + dA0s0]); \
        gl_lds16(gA0s1 + (KT) * 64, &LDS[(BUFS) + dA0s1]); } while (0)
#define STG_A1(KT, BUFS) do { \
        gl_lds16(gA0s0 + 64 * DIM + (KT) * 64, &LDS[(BUFS) + dA0s0 + 64 * 64]); \
        gl_lds16(gA0s1 + 64 * DIM + (KT) * 64, &LDS[(BUFS) + dA0s1 + 64 * 64]); } while (0)
#define STG_B0(KT, BUFS) do { \
        gl_lds16(gB0s0 + (KT) * 64, &LDS[(BUFS) + 16384 + dB0s0]); \
        gl_lds16(gB0s1 + (KT) * 64, &LDS[(BUFS) + 16384 + dB0s1]); } while (0)
#define STG_B1(KT, BUFS) do { \
        gl_lds16(gB0s0 + 32 * DIM + (KT) * 64, &LDS[(BUFS) + 16384 + dB0s0 + 32 * 64]); \
        gl_lds16(gB0s1 + 32 * DIM + (KT) * 64, &LDS[(BUFS) + 16384 + dB0s1 + 32 * 64]); } while (0)

    f32x4 acc[8][4];
#pragma unroll
    for (int i = 0; i < 8; ++i)
#pragma unroll
        for (int j = 0; j < 4; ++j) acc[i][j] = (f32x4){0.f, 0.f, 0.f, 0.f};

    // prologue: KT0 full -> buf0 (oldest 8 loads); KT1 {A0,B0} -> buf1
    STG_A0(0, 0); STG_B0(0, 0); STG_A1(0, 0); STG_B1(0, 0);
    STG_A0(1, 32768); STG_B0(1, 32768);
    asm volatile("s_waitcnt vmcnt(4)");
    __builtin_amdgcn_sched_barrier(0);
    __builtin_amdgcn_s_barrier();

    short8 af[4][2], bf0[2][2], bf1[2][2];
#pragma unroll
    for (int kt = 0; kt < 4; ++kt) {
        const unsigned short* LB = &LDS[(kt & 1) << 15];
        const int cbufS = (kt & 1) << 15;
        const int obufS = cbufS ^ 32768;
        // ---- phase 1 (mh0,nh0)
        dsr_a<0>(LB, wr, l15, l7, quad, af);
        dsr_b<0>(LB, wc, l15, l7, quad, bf0);
        if (kt + 1 < 4) STG_A1(kt + 1, obufS);
        __builtin_amdgcn_s_barrier();
        asm volatile("s_waitcnt lgkmcnt(0)");
        __builtin_amdgcn_sched_barrier(0);
        __builtin_amdgcn_s_setprio(1);
        mma8<0, 0>(af, bf0, acc);
        __builtin_amdgcn_s_setprio(0);
        __builtin_amdgcn_s_barrier();
        // ---- phase 2 (mh0,nh1)
        dsr_b<1>(LB, wc, l15, l7, quad, bf1);
        if (kt + 1 < 4) STG_B1(kt + 1, obufS);
        __builtin_amdgcn_s_barrier();
        asm volatile("s_waitcnt lgkmcnt(0)");
        __builtin_amdgcn_sched_barrier(0);
        __builtin_amdgcn_s_setprio(1);
        mma8<0, 1>(af, bf1, acc);
        __builtin_amdgcn_s_setprio(0);
        __builtin_amdgcn_s_barrier();
        // ---- phase 3 (mh1,nh0)
        dsr_a<1>(LB, wr, l15, l7, quad, af);
        if (kt + 2 < 4) STG_A0(kt + 2, cbufS);
        __builtin_amdgcn_s_barrier();
        asm volatile("s_waitcnt lgkmcnt(0)");
        __builtin_amdgcn_sched_barrier(0);
        __builtin_amdgcn_s_setprio(1);
        mma8<1, 0>(af, bf0, acc);
        __builtin_amdgcn_s_setprio(0);
        __builtin_amdgcn_s_barrier();
        // ---- phase 4 (mh1,nh1)
        if (kt + 2 < 4) STG_B0(kt + 2, cbufS);
        __builtin_amdgcn_s_barrier();
        __builtin_amdgcn_s_setprio(1);
        mma8<1, 1>(af, bf1, acc);
        __builtin_amdgcn_s_setprio(0);
        if (kt < 2) {
            asm volatile("s_waitcnt vmcnt(4)");
            __builtin_amdgcn_sched_barrier(0);
        } else if (kt == 2) {
            asm volatile("s_waitcnt vmcnt(0)");
            __builtin_amdgcn_sched_barrier(0);
        }
        __builtin_amdgcn_s_barrier();
    }
#undef STG_A0
#undef STG_A1
#undef STG_B0
#undef STG_B1

    // epilogue: group-min (16 codes = one M-frag) via 3 fmin + 2 shfl.
    // outl[g_local][pt_local], 16x256 fp32 = 16KB in freed LDS.
    float* outl = (float*)LDS;
#pragma unroll
    for (int m = 0; m < 8; ++m) {
        const float4 en4 = *(const float4*)&en[cBase + wr * 128 + m * 16 + quad * 4];
#pragma unroll
        for (int n = 0; n < 4; ++n) {
            f32x4 a = acc[m][n];
            float d0 = fmaf(-2.f, a[0], en4.x);
            float d1 = fmaf(-2.f, a[1], en4.y);
            float d2 = fmaf(-2.f, a[2], en4.z);
            float d3 = fmaf(-2.f, a[3], en4.w);
            float dm = fminf(fminf(d0, d1), fminf(d2, d3));
            dm = fminf(dm, __shfl_xor(dm, 16));
            dm = fminf(dm, __shfl_xor(dm, 32));
            if (quad == 0)
                outl[(wr * 8 + m) * 256 + wc * 64 + n * 16 + l15] = dm;
        }
    }
    __syncthreads();
    // coalesced gmin write: block covers gmin[pBase..+255][cb*16..+15]
    {
        const int pt = t >> 1, h = t & 1;
#pragma unroll
        for (int q2 = 0; q2 < 2; ++q2) {
            const int g0 = (h * 2 + q2) * 4;
            float4 v;
            v.x = outl[(g0 + 0) * 256 + pt];
            v.y = outl[(g0 + 1) * 256 + pt];
            v.z = outl[(g0 + 2) * 256 + pt];
            v.w = outl[(g0 + 3) * 256 + pt];
            *(float4*)&gmin[(size_t)(pBase + pt) * 512 + cb * 16 + g0] = v;
        }
    }
}

// ---------------------------------------------------------------------------
// Phase 2: one wave per point. Approx global min over 512 group minima;
// rescore flagged groups exactly in fp32, reading emb ROWS cooperatively.
// Groups are LINEAR: group gid = codes [gid*16, gid*16+16).
__global__ __launch_bounds__(256) void k_phase2(
    const float* __restrict__ z, const float* __restrict__ emb,
    const float* __restrict__ A, const float* __restrict__ en,
    const float* __restrict__ gmin,
    int* __restrict__ widx, float* __restrict__ out1,
    int* __restrict__ cnt) {
    int wpt = (blockIdx.x << 2) + (threadIdx.x >> 6);  // point id
    int l = threadIdx.x & 63;

    const float* gp = gmin + (size_t)wpt * 512;
    float loc[8];
    #pragma unroll
    for (int i = 0; i < 8; ++i) loc[i] = gp[i * 64 + l];
    float m8 = loc[0];
    #pragma unroll
    for (int i = 1; i < 8; ++i) m8 = fminf(m8, loc[i]);
    #pragma unroll
    for (int off = 1; off < 64; off <<= 1) m8 = fminf(m8, __shfl_xor(m8, off));
    const float thresh = m8 + MARGIN;

    const float4 z4 = *(const float4*)(z + (size_t)wpt * DIM + 4 * l);
    const float Azn = A[wpt];
    unsigned long long best = ~0ull;
    #pragma unroll 1
    for (int i = 0; i < 8; ++i) {
        unsigned long long mask = __ballot(loc[i] <= thresh);
        while (mask) {
            int s = __ffsll((long long)mask) - 1;
            mask &= mask - 1;
            int cbase = (i * 64 + s) << 4;   // linear groups
            #pragma unroll 4
            for (int k = 0; k < 16; ++k) {
                int c = cbase + k;
                const float4 ev = *(const float4*)(emb + (size_t)c * DIM + 4 * l);
                float p = fmaf(z4.x, ev.x,
                          fmaf(z4.y, ev.y,
                          fmaf(z4.z, ev.z, z4.w * ev.w)));
                #pragma unroll
                for (int off = 1; off < 64; off <<= 1) p += __shfl_xor(p, off);
                float dist = (Azn - 2.0f * p) + en[c];
                unsigned long long pk =
                    ((unsigned long long)f2ord(dist) << 32) | (unsigned)c;
                best = pk < best ? pk : best;
            }
        }
    }
    if (l == 0) {
        int idx = (int)(unsigned)best;
        widx[wpt] = idx;
        out1[wpt] = (float)idx;
        atomicAdd(cnt + idx, 1);
    }
}

// ---------------------------------------------------------------------------
// single block: exclusive prefix of cnt -> offs (+cursor copy);
// out4 = ecs*0.99 + cnt*0.01; n = sum(out4); smoothed -> s_out.
__global__ __launch_bounds__(256) void k_scan(const int* __restrict__ cnt,
                                              const float* __restrict__ ecs,
                                              int* __restrict__ offs,
                                              int* __restrict__ cursor,
                                              float* __restrict__ out4,
                                              float* __restrict__ s_out) {
    __shared__ int ps[256];
    __shared__ double rd[256];
    __shared__ float nsh;
    int t = threadIdx.x;
    int base = t * 32;
    int loc[32];
    int s = 0;
    double nl = 0.0;
    #pragma unroll
    for (int i = 0; i < 32; ++i) {
        int c = cnt[base + i];
        loc[i] = c;
        s += c;
        float f = ecs[base + i] * DECAYF + (float)c * ONE_MINUS_DECAYF;
        out4[base + i] = f;
        nl += (double)f;
    }
    ps[t] = s;
    rd[t] = nl;
    __syncthreads();
    for (int off = 1; off < 256; off <<= 1) {
        int v = (t >= off) ? ps[t - off] : 0;
        __syncthreads();
        ps[t] += v;
        __syncthreads();
    }
    for (int off = 128; off > 0; off >>= 1) {
        if (t < off) rd[t] += rd[t + off];
        __syncthreads();
    }
    if (t == 0) nsh = (float)rd[0];
    __syncthreads();
    int run = (t == 0) ? 0 : ps[t - 1];
    #pragma unroll
    for (int i = 0; i < 32; ++i) {
        offs[base + i] = run;
        cursor[base + i] = run;
        run += loc[i];
    }
    float n = nsh;
    for (int k = t; k < NCODES; k += 256)
        s_out[k] = (out4[k] + EPSF) / (n + KEPSF) * n;
}

// ---------------------------------------------------------------------------
__global__ __launch_bounds__(256) void k_place(const int* __restrict__ widx,
                                               int* __restrict__ cursor,
                                               int* __restrict__ plist) {
    int p = blockIdx.x * 256 + threadIdx.x;
    int idx = widx[p];
    int slot = atomicAdd(&cursor[idx], 1);
    plist[slot] = p;
}

// ---------------------------------------------------------------------------
// z_q_st + commitment-loss partials (no atomics; one double per block)
__global__ __launch_bounds__(256) void k_zq(const float* __restrict__ z,
                                            const float* __restrict__ emb,
                                            const int* __restrict__ widx,
                                            float* __restrict__ out0,
                                            double* __restrict__ part) {
    __shared__ double sred[4];
    int w = (blockIdx.x * blockDim.x + threadIdx.x) >> 6;  // point id
    int wv = threadIdx.x >> 6;
    int lane = threadIdx.x & 63;
    int idx = widx[w];
    const float4 zv = *(const float4*)(z + (size_t)w * DIM + 4 * lane);
    const float4 ev = *(const float4*)(emb + (size_t)idx * DIM + 4 * lane);

    float4 o;
    o.x = ev.x + (zv.x - ev.x);
    o.y = ev.y + (zv.y - ev.y);
    o.z = ev.z + (zv.z - ev.z);
    o.w = ev.w + (zv.w - ev.w);
    *(float4*)(out0 + (size_t)w * DIM + 4 * lane) = o;

    float t0 = ev.x - zv.x, t1 = ev.y - zv.y, t2 = ev.z - zv.z, t3 = ev.w - zv.w;
    float s0 = t0 * t0, s1 = t1 * t1, s2 = t2 * t2, s3 = t3 * t3;
    double ls = (double)s0 + (double)s1 + (double)s2 + (double)s3;
    #pragma unroll
    for (int off = 32; off > 0; off >>= 1) ls += __shfl_down(ls, off);
    if (lane == 0) sred[wv] = ls;
    __syncthreads();
    if (threadIdx.x == 0)
        part[blockIdx.x] = (sred[0] + sred[1]) + (sred[2] + sred[3]);
}

// ---------------------------------------------------------------------------
// single block: sum 8192 loss partials -> out2
__global__ __launch_bounds__(256) void k_loss(const double* __restrict__ part,
                                              float* __restrict__ out2) {
    __shared__ double red[256];
    int t = threadIdx.x;
    double s = 0.0;
    for (int i = t; i < NPTS / 4; i += 256) s += part[i];
    red[t] = s;
    __syncthreads();
    for (int off = 128; off > 0; off >>= 1) {
        if (t < off) red[t] += red[t + off];
        __syncthreads();
    }
    if (t == 0)
        out2[0] = 0.25f * (float)(red[0] / (double)((size_t)NPTS * DIM));
}

// ---------------------------------------------------------------------------
// one wave per code: out5 = 0.99*eem + 0.01*sum(z[points of code])
__global__ __launch_bounds__(256) void k_dw(const float* __restrict__ z,
                                            const float* __restrict__ eem,
                                            const int* __restrict__ offs,
                                            const int* __restrict__ cnt,
                                            const int* __restrict__ plist,
                                            float* __restrict__ out5) {
    int c = blockIdx.x * 4 + (threadIdx.x >> 6);
    int lane = threadIdx.x & 63;
    int beg = offs[c], num = cnt[c];
    float4 acc = make_float4(0.f, 0.f, 0.f, 0.f);
    for (int j = 0; j < num; ++j) {
        int p = plist[beg + j];
        const float4 v = *(const float4*)(z + (size_t)p * DIM + 4 * lane);
        acc.x += v.x; acc.y += v.y; acc.z += v.z; acc.w += v.w;
    }
    const float4 e = *(const float4*)(eem + (size_t)c * DIM + 4 * lane);
    float4 o;
    o.x = e.x * DECAYF + acc.x * ONE_MINUS_DECAYF;
    o.y = e.y * DECAYF + acc.y * ONE_MINUS_DECAYF;
    o.z = e.z * DECAYF + acc.z * ONE_MINUS_DECAYF;
    o.w = e.w * DECAYF + acc.w * ONE_MINUS_DECAYF;
    *(float4*)(out5 + (size_t)c * DIM + 4 * lane) = o;
}

// ---------------------------------------------------------------------------
__global__ __launch_bounds__(256) void k_final(const float* __restrict__ out5,
                                               const float* __restrict__ s,
                                               float* __restrict__ out3) {
    int i = blockIdx.x * blockDim.x + threadIdx.x;
    int stride = gridDim.x * blockDim.x;
    for (int j = i; j < NCODES * DIM; j += stride)
        out3[j] = out5[j] / s[j >> 8];
}

// ---------------------------------------------------------------------------
extern "C" void kernel_launch(void* const* d_in, const int* in_sizes, int n_in,
                              void* d_out, int out_size, void* d_ws, size_t ws_size,
                              hipStream_t stream) {
    const float* z   = (const float*)d_in[0];
    const float* emb = (const float*)d_in[1];
    const float* ecs = (const float*)d_in[2];
    const float* eem = (const float*)d_in[3];

    float* out = (float*)d_out;
    float* out0 = out;                   // z_q_st         [8388608]
    float* out1 = out + 8388608;         // indices        [32768]
    float* out2 = out + 8421376;         // vq_loss        [1]
    float* out3 = out + 8421377;         // new_embedding  [2097152]
    float* out4 = out + 10518529;        // new_ema_cs     [8192]
    float* out5 = out + 10526721;        // new_ema_emb    [2097152]

    char* ws = (char*)d_ws;
    double* wPart = (double*)(ws + WS_PART);
    float*  wA    = (float*)(ws + WS_A);
    float*  wEn   = (float*)(ws + WS_EN);
    int*    wCnt  = (int*)(ws + WS_CNT);
    float*  wS    = (float*)(ws + WS_S);
    int*    wIdx  = (int*)(ws + WS_IDX);
    int*    wOffs = (int*)(ws + WS_OFFS);
    int*    wCur  = (int*)(ws + WS_CUR);
    int*    wPl   = (int*)(ws + WS_PLIST);
    float*  wGmin = (float*)(ws + WS_GMIN);
    unsigned short* wAh = (unsigned short*)(ws + WS_AH);
    unsigned short* wBh = (unsigned short*)(ws + WS_BH);

    hipLaunchKernelGGL(k_prep0, dim3(32), dim3(256), 0, stream, wCnt);
    hipLaunchKernelGGL(k_rownorm, dim3(NPTS / 4), dim3(256), 0, stream, z, wA, NPTS);
    hipLaunchKernelGGL(k_rownorm, dim3(NCODES / 4), dim3(256), 0, stream, emb, wEn, NCODES);
    hipLaunchKernelGGL(k_split, dim3(4096), dim3(256), 0, stream, z, wAh, NPTS * DIM);
    hipLaunchKernelGGL(k_split, dim3(1024), dim3(256), 0, stream, emb, wBh, NCODES * DIM);
    hipLaunchKernelGGL(k_gemm_argmin, dim3((NPTS / 256) * (NCODES / 256)), dim3(512), 0, stream,
                       wAh, wBh, wEn, wGmin);
    hipLaunchKernelGGL(k_phase2, dim3(NPTS / 4), dim3(256), 0, stream,
                       z, emb, wA, wEn, wGmin, wIdx, out1, wCnt);
    hipLaunchKernelGGL(k_scan, dim3(1), dim3(256), 0, stream,
                       wCnt, ecs, wOffs, wCur, out4, wS);
    hipLaunchKernelGGL(k_place, dim3(NPTS / 256), dim3(256), 0, stream, wIdx, wCur, wPl);
    hipLaunchKernelGGL(k_zq, dim3(NPTS / 4), dim3(256), 0, stream, z, emb, wIdx, out0, wPart);
    hipLaunchKernelGGL(k_loss, dim3(1), dim3(256), 0, stream, wPart, out2);
    hipLaunchKernelGGL(k_dw, dim3(NCODES / 4), dim3(256), 0, stream,
                       z, eem, wOffs, wCnt, wPl, out5);
    hipLaunchKernelGGL(k_final, dim3(2048), dim3(256), 0, stream, out5, wS, out3);
}